// Round 5
// baseline (693.380 us; speedup 1.0000x reference)
//
#include <hip/hip_runtime.h>
#include <math.h>

#define NRAYS 8192
#define NSAMP 256
#define GD    160
#define NVOX  (GD*GD*GD)
#define CF    12
#define HID   128
#define RPB   8            // rays per block -> 1024 blocks
#define W0P   56           // temp W0^T pitch (bf16): stride 28 words, 8 bank-starts
#define W1P   136          // s_w1a row pitch (bf16): stride 68 words, 8 bank-starts

#define WS_NEED ((size_t)NVOX * 16)   // packed voxel: 12 fp8 feat + fp32 density

static constexpr float ACT_SHIFT = -13.815509557963774f;
static constexpr float EPSF      = 1e-10f;

typedef __attribute__((ext_vector_type(8)))  short bf16x8;
typedef __attribute__((ext_vector_type(16))) float f32x16;
typedef __attribute__((ext_vector_type(2)))  float f32x2;

union FragU { unsigned u[4]; uint4 q; bf16x8 v; };

__device__ __forceinline__ unsigned short bf16rne(float f) {
    unsigned u = __float_as_uint(f);
    return (unsigned short)((u + 0x7FFFu + ((u >> 16) & 1u)) >> 16);
}
// pack two fp32 -> bf16x2 (truncate): low half = lo, high half = hi
__device__ __forceinline__ unsigned pack2(float lo, float hi) {
    return __builtin_amdgcn_perm(__float_as_uint(hi), __float_as_uint(lo), 0x07060302u);
}
__device__ __forceinline__ bf16x8 ld_frag(const unsigned short* p) {
    FragU f; f.q = *(const uint4*)p; return f.v;
}

// ---------------- prepack: density+k0 -> {12 x fp8 feat, fp32 dens} ----------
__global__ __launch_bounds__(256)
void dvgo_prepack(const float* __restrict__ density_grid,
                  const float* __restrict__ k0,
                  uint4* __restrict__ pk)
{
    int v = blockIdx.x * 256 + threadIdx.x;
    if (v >= NVOX) return;
    const float4* kp = (const float4*)(k0 + (size_t)v * CF);
    float4 a = kp[0], b = kp[1], c = kp[2];
    uint4 o;
    int wa = __builtin_amdgcn_cvt_pk_fp8_f32(a.x, a.y, 0, false);
    wa     = __builtin_amdgcn_cvt_pk_fp8_f32(a.z, a.w, wa, true);
    int wb = __builtin_amdgcn_cvt_pk_fp8_f32(b.x, b.y, 0, false);
    wb     = __builtin_amdgcn_cvt_pk_fp8_f32(b.z, b.w, wb, true);
    int wc = __builtin_amdgcn_cvt_pk_fp8_f32(c.x, c.y, 0, false);
    wc     = __builtin_amdgcn_cvt_pk_fp8_f32(c.z, c.w, wc, true);
    o.x = (unsigned)wa; o.y = (unsigned)wb; o.z = (unsigned)wc;
    o.w = __float_as_uint(density_grid[v]);
    pk[v] = o;
}

__device__ __forceinline__ void acc_vox(uint4 q, float wc,
                                        float (&feat)[CF], float& dens) {
    unsigned u[3] = {q.x, q.y, q.z};
    #pragma unroll
    for (int i = 0; i < 3; ++i) {
        f32x2 lo = __builtin_amdgcn_cvt_pk_f32_fp8((int)u[i], false);
        f32x2 hi = __builtin_amdgcn_cvt_pk_f32_fp8((int)u[i], true);
        feat[4*i+0] = fmaf(lo.x, wc, feat[4*i+0]);
        feat[4*i+1] = fmaf(lo.y, wc, feat[4*i+1]);
        feat[4*i+2] = fmaf(hi.x, wc, feat[4*i+2]);
        feat[4*i+3] = fmaf(hi.y, wc, feat[4*i+3]);
    }
    dens = fmaf(__uint_as_float(q.w), wc, dens);
}

__device__ __forceinline__ void addr_calc(float px, float py, float pz,
                                          float& fx, float& fy, float& fz, int& base) {
    px = fminf(fmaxf(px, 0.f), 1.f) * (float)(GD - 1);
    py = fminf(fmaxf(py, 0.f), 1.f) * (float)(GD - 1);
    pz = fminf(fmaxf(pz, 0.f), 1.f) * (float)(GD - 1);
    int ix = min((int)px, GD - 2);
    int iy = min((int)py, GD - 2);
    int iz = min((int)pz, GD - 2);
    fx = px - (float)ix; fy = py - (float)iy; fz = pz - (float)iz;
    base = (ix * GD + iy) * GD + iz;
}

// ---------------- fused main kernel ------------------------------------------
template<bool PACKED>
__global__ __launch_bounds__(256, 3)
void dvgo_mfma(const float* __restrict__ ray_pts,
               const float* __restrict__ viewdirs,
               const float* __restrict__ density_grid,
               const float* __restrict__ k0,
               const uint4* __restrict__ pk,
               const float* __restrict__ w0,
               const float* __restrict__ b0,
               const float* __restrict__ w1,
               const float* __restrict__ b1,
               const float* __restrict__ w2,
               const float* __restrict__ b2,
               float* __restrict__ out)
{
    __shared__ __align__(16) unsigned short s_w1a[HID * W1P];  // 34.8 KB (doubles as W0 temp)
    __shared__ __align__(16) float4 s_w2b[HID];                // 2 KB
    __shared__ __align__(16) unsigned s_vpk[RPB][16];          // per-ray vemb packs
    __shared__ float s_wtot[2][4];
    __shared__ float s_red[2][4][3];

    const int t    = threadIdx.x;
    const int lane = t & 63;
    const int w    = t >> 6;
    const int nidx = lane & 31;
    const int qh   = lane >> 5;

    // ---- phase 1: stage W0^T (bf16) through s_w1a, load A-frags to regs ------
    for (int e = t; e < 39 * HID; e += 256) {
        int i = e >> 7, o = e & 127;
        s_w1a[o * W0P + i] = bf16rne(w0[e]);
    }
    if (t < HID) {
        s_w1a[t * W0P + 39] = bf16rne(b0[t]);
        #pragma unroll
        for (int i = 40; i < 48; ++i) s_w1a[t * W0P + i] = 0;
    }
    __syncthreads();
    bf16x8 w0f[4][3];
    #pragma unroll
    for (int mt = 0; mt < 4; ++mt)
        #pragma unroll
        for (int kk = 0; kk < 3; ++kk)
            w0f[mt][kk] = ld_frag(&s_w1a[(nidx + mt * 32) * W0P + qh * 8 + kk * 16]);
    __syncthreads();

    // ---- phase 2: stage W1^T + w2b + vemb ------------------------------------
    for (int e = t; e < HID * HID; e += 256) {
        int i = e >> 7, o = e & 127;
        s_w1a[o * W1P + i] = bf16rne(w1[e]);
    }
    if (t < HID)
        s_w2b[t] = make_float4(w2[t * 3 + 0], w2[t * 3 + 1], w2[t * 3 + 2], b1[t]);
    if (t < RPB) {
        int ray = blockIdx.x * RPB + t;
        float vx = viewdirs[ray * 3 + 0], vy = viewdirs[ray * 3 + 1], vz = viewdirs[ray * 3 + 2];
        float inv = 1.0f / (sqrtf(vx * vx + vy * vy + vz * vz) + EPSF);
        float ve[27];
        ve[0] = vx * inv; ve[1] = vy * inv; ve[2] = vz * inv;
        #pragma unroll
        for (int i = 0; i < 3; ++i)
            #pragma unroll
            for (int f = 0; f < 4; ++f) {
                float ang = ve[i] * (float)(1 << f);
                ve[3  + i * 4 + f] = __sinf(ang);
                ve[15 + i * 4 + f] = __cosf(ang);
            }
        #pragma unroll
        for (int p2i = 0; p2i < 13; ++p2i) s_vpk[t][p2i] = pack2(ve[2 * p2i], ve[2 * p2i + 1]);
        s_vpk[t][13] = pack2(ve[26], 1.0f);      // ones-row at k=39
        s_vpk[t][14] = 0u; s_vpk[t][15] = 0u;
    }
    const float b2x = b2[0], b2y = b2[1], b2z = b2[2];
    __syncthreads();

    const int nray = blockIdx.x * RPB;

    // ---- gather pipeline state (PACKED path) ---------------------------------
    uint4 q[8];
    float cfx = 0.f, cfy = 0.f, cfz = 0.f;      // frac weights for ray being consumed
    float rpx = 0.f, rpy = 0.f, rpz = 0.f;      // ray_pts one stage ahead
    if (PACKED) {
        // issue ray 0's voxel loads
        float px = ray_pts[(nray * NSAMP + t) * 3 + 0];
        float py = ray_pts[(nray * NSAMP + t) * 3 + 1];
        float pz = ray_pts[(nray * NSAMP + t) * 3 + 2];
        int base;
        addr_calc(px, py, pz, cfx, cfy, cfz, base);
        const uint4* p00 = pk + base;
        const uint4* p01 = pk + (base + GD);
        const uint4* p10 = pk + (base + GD * GD);
        const uint4* p11 = pk + (base + GD * GD + GD);
        q[0] = p00[0]; q[1] = p00[1];
        q[2] = p01[0]; q[3] = p01[1];
        q[4] = p10[0]; q[5] = p10[1];
        q[6] = p11[0]; q[7] = p11[1];
        // prefetch ray 1's points
        int r1 = nray + ((RPB > 1) ? 1 : 0);
        rpx = ray_pts[(r1 * NSAMP + t) * 3 + 0];
        rpy = ray_pts[(r1 * NSAMP + t) * 3 + 1];
        rpz = ray_pts[(r1 * NSAMP + t) * 3 + 2];
    }

    #pragma unroll 1
    for (int j = 0; j < RPB; ++j) {
        const int ray = nray + j;
        const int par = j & 1;

        float dens = 0.f;
        float feat[CF];
        #pragma unroll
        for (int c = 0; c < CF; ++c) feat[c] = 0.f;

        if (PACKED) {
            // ---- consume ray j's prefetched voxels ---------------------------
            float wx[2] = {1.f - cfx, cfx}, wy[2] = {1.f - cfy, cfy}, wz[2] = {1.f - cfz, cfz};
            acc_vox(q[0], wx[0] * wy[0] * wz[0], feat, dens);
            acc_vox(q[1], wx[0] * wy[0] * wz[1], feat, dens);
            acc_vox(q[2], wx[0] * wy[1] * wz[0], feat, dens);
            acc_vox(q[3], wx[0] * wy[1] * wz[1], feat, dens);
            acc_vox(q[4], wx[1] * wy[0] * wz[0], feat, dens);
            acc_vox(q[5], wx[1] * wy[0] * wz[1], feat, dens);
            acc_vox(q[6], wx[1] * wy[1] * wz[0], feat, dens);
            acc_vox(q[7], wx[1] * wy[1] * wz[1], feat, dens);
            // ---- issue ray j+1's voxel loads (overlap with MLP below) --------
            if (j + 1 < RPB) {
                int base;
                addr_calc(rpx, rpy, rpz, cfx, cfy, cfz, base);
                const uint4* p00 = pk + base;
                const uint4* p01 = pk + (base + GD);
                const uint4* p10 = pk + (base + GD * GD);
                const uint4* p11 = pk + (base + GD * GD + GD);
                q[0] = p00[0]; q[1] = p00[1];
                q[2] = p01[0]; q[3] = p01[1];
                q[4] = p10[0]; q[5] = p10[1];
                q[6] = p11[0]; q[7] = p11[1];
                int j2 = (j + 2 < RPB) ? j + 2 : RPB - 1;
                rpx = ray_pts[((nray + j2) * NSAMP + t) * 3 + 0];
                rpy = ray_pts[((nray + j2) * NSAMP + t) * 3 + 1];
                rpz = ray_pts[((nray + j2) * NSAMP + t) * 3 + 2];
            }
        } else {
            // ---- fallback: direct fp32 gather --------------------------------
            float px = ray_pts[(ray * NSAMP + t) * 3 + 0];
            float py = ray_pts[(ray * NSAMP + t) * 3 + 1];
            float pz = ray_pts[(ray * NSAMP + t) * 3 + 2];
            float fx, fy, fz; int base;
            addr_calc(px, py, pz, fx, fy, fz, base);
            float wx[2] = {1.f - fx, fx}, wy[2] = {1.f - fy, fy}, wz[2] = {1.f - fz, fz};
            #pragma unroll
            for (int dx = 0; dx < 2; ++dx)
            #pragma unroll
            for (int dy = 0; dy < 2; ++dy)
            #pragma unroll
            for (int dz = 0; dz < 2; ++dz) {
                int idx = base + dx * (GD * GD) + dy * GD + dz;
                float wc = wx[dx] * wy[dy] * wz[dz];
                dens = fmaf(density_grid[idx], wc, dens);
                const float4* kp = (const float4*)(k0 + (long)idx * CF);
                float4 a = kp[0], b = kp[1], c = kp[2];
                feat[0]  = fmaf(a.x, wc, feat[0]);  feat[1]  = fmaf(a.y, wc, feat[1]);
                feat[2]  = fmaf(a.z, wc, feat[2]);  feat[3]  = fmaf(a.w, wc, feat[3]);
                feat[4]  = fmaf(b.x, wc, feat[4]);  feat[5]  = fmaf(b.y, wc, feat[5]);
                feat[6]  = fmaf(b.z, wc, feat[6]);  feat[7]  = fmaf(b.w, wc, feat[7]);
                feat[8]  = fmaf(c.x, wc, feat[8]);  feat[9]  = fmaf(c.y, wc, feat[9]);
                feat[10] = fmaf(c.z, wc, feat[10]); feat[11] = fmaf(c.w, wc, feat[11]);
            }
        }

        // ---------------- alpha + product scan (shfl-based) -------------------
        float sv    = dens + ACT_SHIFT;
        float rs    = rsqrtf(1.0f + __expf(sv));
        float alpha = 1.0f - rs;
        float x     = rs + EPSF;
        #pragma unroll
        for (int off = 1; off < 64; off <<= 1) {
            float y = __shfl_up(x, off);
            if (lane >= off) x *= y;
        }
        if (lane == 63) s_wtot[par][w] = x;
        __syncthreads();
        float t0 = s_wtot[par][0], t1 = s_wtot[par][1];
        float t2 = s_wtot[par][2], t3 = s_wtot[par][3];
        float pre = 1.f;
        if (w > 0) pre *= t0;
        if (w > 1) pre *= t1;
        if (w > 2) pre *= t2;
        const float ainv = t0 * t1 * t2 * t3;
        float ex = __shfl_up(x, 1);
        if (lane == 0) ex = 1.f;
        const float wgt = alpha * ex * pre;

        // ---------------- vemb packs from LDS (broadcast) ---------------------
        uint4 va = *(const uint4*)&s_vpk[j][0];
        uint4 vb = *(const uint4*)&s_vpk[j][4];
        uint4 vc = *(const uint4*)&s_vpk[j][8];
        uint4 vd = *(const uint4*)&s_vpk[j][12];

        // ---------------- feat packs + layer0 B-frags -------------------------
        unsigned flo[4], fhi[2];
        #pragma unroll
        for (int r = 0; r < 4; ++r) flo[r] = pack2(feat[2 * r], feat[2 * r + 1]);
        fhi[0] = pack2(feat[8], feat[9]);
        fhi[1] = pack2(feat[10], feat[11]);

        FragU bf[2][3];
        #pragma unroll
        for (int nt = 0; nt < 2; ++nt) {
            int src = nt * 32 + nidx;
            unsigned m0 = __shfl(flo[0], src), m1 = __shfl(flo[1], src);
            unsigned m2 = __shfl(flo[2], src), m3 = __shfl(flo[3], src);
            unsigned h0 = __shfl(fhi[0], src), h1 = __shfl(fhi[1], src);
            bf[nt][0].u[0] = qh ? h0 : m0;
            bf[nt][0].u[1] = qh ? h1 : m1;
            bf[nt][0].u[2] = qh ? va.x : m2;
            bf[nt][0].u[3] = qh ? va.y : m3;
            bf[nt][1].u[0] = qh ? vb.z : va.z;
            bf[nt][1].u[1] = qh ? vb.w : va.w;
            bf[nt][1].u[2] = qh ? vc.x : vb.x;
            bf[nt][1].u[3] = qh ? vc.y : vb.y;
            bf[nt][2].u[0] = qh ? 0u : vc.z;
            bf[nt][2].u[1] = qh ? 0u : vc.w;
            bf[nt][2].u[2] = qh ? 0u : vd.x;
            bf[nt][2].u[3] = qh ? 0u : vd.y;
        }

        // ---------------- layer0 MFMA + C->B transition -----------------------
        FragU hf0[8], hf1[8];
        #pragma unroll
        for (int mt = 0; mt < 4; ++mt) {
            f32x16 aA = {}, aB = {};
            #pragma unroll
            for (int kk = 0; kk < 3; ++kk) {
                aA = __builtin_amdgcn_mfma_f32_32x32x16_bf16(w0f[mt][kk], bf[0][kk].v, aA, 0, 0, 0);
                aB = __builtin_amdgcn_mfma_f32_32x32x16_bf16(w0f[mt][kk], bf[1][kk].v, aB, 0, 0, 0);
            }
            #pragma unroll
            for (int nt = 0; nt < 2; ++nt) {
                const f32x16& ac = nt ? aB : aA;
                FragU* hf = nt ? hf1 : hf0;
                unsigned p[8];
                #pragma unroll
                for (int r2 = 0; r2 < 8; ++r2)
                    p[r2] = pack2(fmaxf(ac[2 * r2], 0.f), fmaxf(ac[2 * r2 + 1], 0.f));
                unsigned g0[8], g1[8];
                #pragma unroll
                for (int r2 = 0; r2 < 8; ++r2) {
                    g0[r2] = __shfl(p[r2], nidx);
                    g1[r2] = __shfl(p[r2], nidx + 32);
                }
                hf[2 * mt + 0].u[0] = qh ? g0[2] : g0[0];
                hf[2 * mt + 0].u[1] = qh ? g0[3] : g0[1];
                hf[2 * mt + 0].u[2] = qh ? g1[2] : g1[0];
                hf[2 * mt + 0].u[3] = qh ? g1[3] : g1[1];
                hf[2 * mt + 1].u[0] = qh ? g0[6] : g0[4];
                hf[2 * mt + 1].u[1] = qh ? g0[7] : g0[5];
                hf[2 * mt + 1].u[2] = qh ? g1[6] : g1[4];
                hf[2 * mt + 1].u[3] = qh ? g1[7] : g1[5];
            }
        }

        // ---------------- layer1 MFMA + layer2 (fp32 VALU) --------------------
        float rA0 = 0.f, rA1 = 0.f, rA2 = 0.f;
        float rB0 = 0.f, rB1 = 0.f, rB2 = 0.f;
        const unsigned short* w1row = &s_w1a[nidx * W1P + qh * 8];
        #pragma unroll
        for (int mt2 = 0; mt2 < 4; ++mt2) {
            f32x16 cA = {}, cB = {};
            #pragma unroll
            for (int kk = 0; kk < 8; ++kk) {
                bf16x8 af = ld_frag(w1row + mt2 * 32 * W1P + kk * 16);
                cA = __builtin_amdgcn_mfma_f32_32x32x16_bf16(af, hf0[kk].v, cA, 0, 0, 0);
                cB = __builtin_amdgcn_mfma_f32_32x32x16_bf16(af, hf1[kk].v, cB, 0, 0, 0);
            }
            #pragma unroll
            for (int reg = 0; reg < 16; ++reg) {
                int dim = mt2 * 32 + (reg & 3) + 8 * (reg >> 2) + 4 * qh;
                float4 wb = s_w2b[dim];
                float hvA = fmaxf(cA[reg] + wb.w, 0.f);
                rA0 = fmaf(hvA, wb.x, rA0); rA1 = fmaf(hvA, wb.y, rA1); rA2 = fmaf(hvA, wb.z, rA2);
                float hvB = fmaxf(cB[reg] + wb.w, 0.f);
                rB0 = fmaf(hvB, wb.x, rB0); rB1 = fmaf(hvB, wb.y, rB1); rB2 = fmaf(hvB, wb.z, rB2);
            }
        }

        rA0 += __shfl_xor(rA0, 32); rA1 += __shfl_xor(rA1, 32); rA2 += __shfl_xor(rA2, 32);
        rB0 += __shfl_xor(rB0, 32); rB1 += __shfl_xor(rB1, 32); rB2 += __shfl_xor(rB2, 32);

        float wgtA = __shfl(wgt, nidx);
        float wgtB = __shfl(wgt, nidx + 32);
        float cA0 = wgtA * __builtin_amdgcn_rcpf(1.f + __expf(-(rA0 + b2x)));
        float cA1 = wgtA * __builtin_amdgcn_rcpf(1.f + __expf(-(rA1 + b2y)));
        float cA2 = wgtA * __builtin_amdgcn_rcpf(1.f + __expf(-(rA2 + b2z)));
        float cB0 = wgtB * __builtin_amdgcn_rcpf(1.f + __expf(-(rB0 + b2x)));
        float cB1 = wgtB * __builtin_amdgcn_rcpf(1.f + __expf(-(rB1 + b2y)));
        float cB2 = wgtB * __builtin_amdgcn_rcpf(1.f + __expf(-(rB2 + b2z)));

        float s0 = (lane < 32) ? (cA0 + cB0) : 0.f;
        float s1 = (lane < 32) ? (cA1 + cB1) : 0.f;
        float s2 = (lane < 32) ? (cA2 + cB2) : 0.f;
        #pragma unroll
        for (int off = 32; off > 0; off >>= 1) {
            s0 += __shfl_down(s0, off);
            s1 += __shfl_down(s1, off);
            s2 += __shfl_down(s2, off);
        }
        if (lane == 0) {
            s_red[par][w][0] = s0; s_red[par][w][1] = s1; s_red[par][w][2] = s2;
        }
        __syncthreads();
        if (t == 0) {
            out[ray * 3 + 0] = s_red[par][0][0] + s_red[par][1][0] + s_red[par][2][0] + s_red[par][3][0] + ainv;
            out[ray * 3 + 1] = s_red[par][0][1] + s_red[par][1][1] + s_red[par][2][1] + s_red[par][3][1] + ainv;
            out[ray * 3 + 2] = s_red[par][0][2] + s_red[par][1][2] + s_red[par][2][2] + s_red[par][3][2] + ainv;
        }
    }
}

extern "C" void kernel_launch(void* const* d_in, const int* in_sizes, int n_in,
                              void* d_out, int out_size, void* d_ws, size_t ws_size,
                              hipStream_t stream) {
    const float* ray_pts      = (const float*)d_in[0];
    const float* viewdirs     = (const float*)d_in[1];
    const float* density_grid = (const float*)d_in[2];
    const float* k0           = (const float*)d_in[3];
    const float* w0           = (const float*)d_in[4];
    const float* b0           = (const float*)d_in[5];
    const float* w1           = (const float*)d_in[6];
    const float* b1           = (const float*)d_in[7];
    const float* w2           = (const float*)d_in[8];
    const float* b2           = (const float*)d_in[9];
    float*       outp         = (float*)d_out;

    if (ws_size >= WS_NEED) {
        uint4* pk = (uint4*)d_ws;
        dvgo_prepack<<<dim3((NVOX + 255) / 256), dim3(256), 0, stream>>>(
            density_grid, k0, pk);
        dvgo_mfma<true><<<dim3(NRAYS / RPB), dim3(256), 0, stream>>>(
            ray_pts, viewdirs, density_grid, k0, pk, w0, b0, w1, b1, w2, b2, outp);
    } else {
        dvgo_mfma<false><<<dim3(NRAYS / RPB), dim3(256), 0, stream>>>(
            ray_pts, viewdirs, density_grid, k0, (const uint4*)d_ws,
            w0, b0, w1, b1, w2, b2, outp);
    }
}

// Round 6
// 516.712 us; speedup vs baseline: 1.3419x; 1.3419x over previous
//
#include <hip/hip_runtime.h>
#include <math.h>

#define NRAYS 8192
#define NSAMP 256
#define GD    160
#define NVOX  (GD*GD*GD)
#define CF    12
#define HID   128
#define RPB   8            // rays per block -> 1024 blocks
#define W0P   56           // s_w0a row pitch (bf16): stride 28 words, 8 bank-starts
#define W1P   136          // s_w1a row pitch (bf16): stride 68 words, 8 bank-starts

#define WS_NEED ((size_t)NVOX * 16)   // packed voxel: 12 fp8 feat + fp32 density

static constexpr float ACT_SHIFT = -13.815509557963774f;
static constexpr float EPSF      = 1e-10f;

typedef __attribute__((ext_vector_type(8)))  short bf16x8;
typedef __attribute__((ext_vector_type(16))) float f32x16;
typedef __attribute__((ext_vector_type(2)))  float f32x2;

union FragU { unsigned u[4]; uint4 q; bf16x8 v; };

__device__ __forceinline__ unsigned short bf16rne(float f) {
    unsigned u = __float_as_uint(f);
    return (unsigned short)((u + 0x7FFFu + ((u >> 16) & 1u)) >> 16);
}
// pack two fp32 -> bf16x2 (truncate): low half = lo, high half = hi
__device__ __forceinline__ unsigned pack2(float lo, float hi) {
    return __builtin_amdgcn_perm(__float_as_uint(hi), __float_as_uint(lo), 0x07060302u);
}
__device__ __forceinline__ bf16x8 ld_frag(const unsigned short* p) {
    FragU f; f.q = *(const uint4*)p; return f.v;
}

// ---------------- prepack: density+k0 -> {12 x fp8 feat, fp32 dens} ----------
__global__ __launch_bounds__(256)
void dvgo_prepack(const float* __restrict__ density_grid,
                  const float* __restrict__ k0,
                  uint4* __restrict__ pk)
{
    int v = blockIdx.x * 256 + threadIdx.x;
    if (v >= NVOX) return;
    const float4* kp = (const float4*)(k0 + (size_t)v * CF);
    float4 a = kp[0], b = kp[1], c = kp[2];
    uint4 o;
    int wa = __builtin_amdgcn_cvt_pk_fp8_f32(a.x, a.y, 0, false);
    wa     = __builtin_amdgcn_cvt_pk_fp8_f32(a.z, a.w, wa, true);
    int wb = __builtin_amdgcn_cvt_pk_fp8_f32(b.x, b.y, 0, false);
    wb     = __builtin_amdgcn_cvt_pk_fp8_f32(b.z, b.w, wb, true);
    int wc = __builtin_amdgcn_cvt_pk_fp8_f32(c.x, c.y, 0, false);
    wc     = __builtin_amdgcn_cvt_pk_fp8_f32(c.z, c.w, wc, true);
    o.x = (unsigned)wa; o.y = (unsigned)wb; o.z = (unsigned)wc;
    o.w = __float_as_uint(density_grid[v]);
    pk[v] = o;
}

__device__ __forceinline__ void acc_vox(uint4 q, float wc,
                                        float (&feat)[CF], float& dens) {
    unsigned u[3] = {q.x, q.y, q.z};
    #pragma unroll
    for (int i = 0; i < 3; ++i) {
        f32x2 lo = __builtin_amdgcn_cvt_pk_f32_fp8((int)u[i], false);
        f32x2 hi = __builtin_amdgcn_cvt_pk_f32_fp8((int)u[i], true);
        feat[4*i+0] = fmaf(lo.x, wc, feat[4*i+0]);
        feat[4*i+1] = fmaf(lo.y, wc, feat[4*i+1]);
        feat[4*i+2] = fmaf(hi.x, wc, feat[4*i+2]);
        feat[4*i+3] = fmaf(hi.y, wc, feat[4*i+3]);
    }
    dens = fmaf(__uint_as_float(q.w), wc, dens);
}

// ---------------- fused main kernel ------------------------------------------
template<bool PACKED>
__global__ __launch_bounds__(256, 3)
void dvgo_mfma(const float* __restrict__ ray_pts,
               const float* __restrict__ viewdirs,
               const float* __restrict__ density_grid,
               const float* __restrict__ k0,
               const uint4* __restrict__ pk,
               const float* __restrict__ w0,
               const float* __restrict__ b0,
               const float* __restrict__ w1,
               const float* __restrict__ b1,
               const float* __restrict__ w2,
               const float* __restrict__ b2,
               float* __restrict__ out)
{
    __shared__ __align__(16) unsigned short s_w1a[HID * W1P];  // 34.8 KB
    __shared__ __align__(16) unsigned short s_w0a[HID * W0P];  // 14.3 KB
    __shared__ __align__(16) float4 s_w2b[HID];                // 2 KB
    __shared__ __align__(16) unsigned s_vpk[RPB][16];          // per-ray vemb packs
    __shared__ float s_wtot[2][4];
    __shared__ float s_red[2][4][3];

    const int t    = threadIdx.x;
    const int lane = t & 63;
    const int w    = t >> 6;
    const int nidx = lane & 31;
    const int qh   = lane >> 5;

    // ---------------- per-block weight staging (bf16, transposed) -------------
    for (int e = t; e < HID * HID; e += 256) {
        int i = e >> 7, o = e & 127;
        s_w1a[o * W1P + i] = bf16rne(w1[e]);
    }
    for (int e = t; e < 39 * HID; e += 256) {
        int i = e >> 7, o = e & 127;
        s_w0a[o * W0P + i] = bf16rne(w0[e]);
    }
    if (t < HID) {
        s_w0a[t * W0P + 39] = bf16rne(b0[t]);
        #pragma unroll
        for (int i = 40; i < 48; ++i) s_w0a[t * W0P + i] = 0;
        s_w2b[t] = make_float4(w2[t * 3 + 0], w2[t * 3 + 1], w2[t * 3 + 2], b1[t]);
    }
    // ---------------- per-block view embedding precompute ---------------------
    if (t < RPB) {
        int ray = blockIdx.x * RPB + t;
        float vx = viewdirs[ray * 3 + 0], vy = viewdirs[ray * 3 + 1], vz = viewdirs[ray * 3 + 2];
        float inv = 1.0f / (sqrtf(vx * vx + vy * vy + vz * vz) + EPSF);
        float ve[27];
        ve[0] = vx * inv; ve[1] = vy * inv; ve[2] = vz * inv;
        #pragma unroll
        for (int i = 0; i < 3; ++i)
            #pragma unroll
            for (int f = 0; f < 4; ++f) {
                float ang = ve[i] * (float)(1 << f);
                ve[3  + i * 4 + f] = __sinf(ang);
                ve[15 + i * 4 + f] = __cosf(ang);
            }
        #pragma unroll
        for (int p2i = 0; p2i < 13; ++p2i) s_vpk[t][p2i] = pack2(ve[2 * p2i], ve[2 * p2i + 1]);
        s_vpk[t][13] = pack2(ve[26], 1.0f);      // ones-row at k=39
        s_vpk[t][14] = 0u; s_vpk[t][15] = 0u;
    }
    const float b2x = b2[0], b2y = b2[1], b2z = b2[2];
    __syncthreads();

    #pragma unroll 1
    for (int j = 0; j < RPB; ++j) {
        const int ray = blockIdx.x * RPB + j;
        const int par = j & 1;

        // ---------------- trilinear gather, sample = t ------------------------
        float px = ray_pts[(ray * NSAMP + t) * 3 + 0];
        float py = ray_pts[(ray * NSAMP + t) * 3 + 1];
        float pz = ray_pts[(ray * NSAMP + t) * 3 + 2];
        px = fminf(fmaxf(px, 0.f), 1.f) * (float)(GD - 1);
        py = fminf(fmaxf(py, 0.f), 1.f) * (float)(GD - 1);
        pz = fminf(fmaxf(pz, 0.f), 1.f) * (float)(GD - 1);
        int ix = min((int)px, GD - 2);
        int iy = min((int)py, GD - 2);
        int iz = min((int)pz, GD - 2);
        float fx = px - (float)ix, fy = py - (float)iy, fz = pz - (float)iz;
        float wx[2] = {1.f - fx, fx}, wy[2] = {1.f - fy, fy}, wz[2] = {1.f - fz, fz};
        int base = (ix * GD + iy) * GD + iz;

        float dens = 0.f;
        float feat[CF];
        #pragma unroll
        for (int c = 0; c < CF; ++c) feat[c] = 0.f;

        if (PACKED) {
            #pragma unroll
            for (int dx = 0; dx < 2; ++dx)
            #pragma unroll
            for (int dy = 0; dy < 2; ++dy) {
                int v0 = base + dx * (GD * GD) + dy * GD;
                const uint4* p0 = pk + v0;
                uint4 q0 = p0[0], q1 = p0[1];
                float wxy = wx[dx] * wy[dy];
                acc_vox(q0, wxy * wz[0], feat, dens);
                acc_vox(q1, wxy * wz[1], feat, dens);
            }
        } else {
            #pragma unroll
            for (int dx = 0; dx < 2; ++dx)
            #pragma unroll
            for (int dy = 0; dy < 2; ++dy)
            #pragma unroll
            for (int dz = 0; dz < 2; ++dz) {
                int idx = base + dx * (GD * GD) + dy * GD + dz;
                float wc = wx[dx] * wy[dy] * wz[dz];
                dens = fmaf(density_grid[idx], wc, dens);
                const float4* kp = (const float4*)(k0 + (long)idx * CF);
                float4 a = kp[0], b = kp[1], c = kp[2];
                feat[0]  = fmaf(a.x, wc, feat[0]);  feat[1]  = fmaf(a.y, wc, feat[1]);
                feat[2]  = fmaf(a.z, wc, feat[2]);  feat[3]  = fmaf(a.w, wc, feat[3]);
                feat[4]  = fmaf(b.x, wc, feat[4]);  feat[5]  = fmaf(b.y, wc, feat[5]);
                feat[6]  = fmaf(b.z, wc, feat[6]);  feat[7]  = fmaf(b.w, wc, feat[7]);
                feat[8]  = fmaf(c.x, wc, feat[8]);  feat[9]  = fmaf(c.y, wc, feat[9]);
                feat[10] = fmaf(c.z, wc, feat[10]); feat[11] = fmaf(c.w, wc, feat[11]);
            }
        }

        // ---------------- alpha + product scan (shfl-based) -------------------
        float sv    = dens + ACT_SHIFT;
        float rs    = rsqrtf(1.0f + __expf(sv));
        float alpha = 1.0f - rs;
        float x     = rs + EPSF;
        #pragma unroll
        for (int off = 1; off < 64; off <<= 1) {
            float y = __shfl_up(x, off);
            if (lane >= off) x *= y;
        }
        if (lane == 63) s_wtot[par][w] = x;
        __syncthreads();
        float t0 = s_wtot[par][0], t1 = s_wtot[par][1];
        float t2 = s_wtot[par][2], t3 = s_wtot[par][3];
        float pre = 1.f;
        if (w > 0) pre *= t0;
        if (w > 1) pre *= t1;
        if (w > 2) pre *= t2;
        const float ainv = t0 * t1 * t2 * t3;
        float ex = __shfl_up(x, 1);
        if (lane == 0) ex = 1.f;
        const float wgt = alpha * ex * pre;

        // ---------------- vemb packs from LDS (broadcast) ---------------------
        uint4 va = *(const uint4*)&s_vpk[j][0];
        uint4 vb = *(const uint4*)&s_vpk[j][4];
        uint4 vc = *(const uint4*)&s_vpk[j][8];
        uint4 vd = *(const uint4*)&s_vpk[j][12];

        // ---------------- feat packs + layer0 B-frags -------------------------
        unsigned flo[4], fhi[2];
        #pragma unroll
        for (int r = 0; r < 4; ++r) flo[r] = pack2(feat[2 * r], feat[2 * r + 1]);
        fhi[0] = pack2(feat[8], feat[9]);
        fhi[1] = pack2(feat[10], feat[11]);

        FragU bf[2][3];
        #pragma unroll
        for (int nt = 0; nt < 2; ++nt) {
            int src = nt * 32 + nidx;
            unsigned m0 = __shfl(flo[0], src), m1 = __shfl(flo[1], src);
            unsigned m2 = __shfl(flo[2], src), m3 = __shfl(flo[3], src);
            unsigned h0 = __shfl(fhi[0], src), h1 = __shfl(fhi[1], src);
            bf[nt][0].u[0] = qh ? h0 : m0;
            bf[nt][0].u[1] = qh ? h1 : m1;
            bf[nt][0].u[2] = qh ? va.x : m2;
            bf[nt][0].u[3] = qh ? va.y : m3;
            bf[nt][1].u[0] = qh ? vb.z : va.z;
            bf[nt][1].u[1] = qh ? vb.w : va.w;
            bf[nt][1].u[2] = qh ? vc.x : vb.x;
            bf[nt][1].u[3] = qh ? vc.y : vb.y;
            bf[nt][2].u[0] = qh ? 0u : vc.z;
            bf[nt][2].u[1] = qh ? 0u : vc.w;
            bf[nt][2].u[2] = qh ? 0u : vd.x;
            bf[nt][2].u[3] = qh ? 0u : vd.y;
        }

        // ---------------- layer0 MFMA + C->B transition (A-frags from LDS) ----
        FragU hf0[8], hf1[8];
        const unsigned short* w0row = &s_w0a[nidx * W0P + qh * 8];
        #pragma unroll
        for (int mt = 0; mt < 4; ++mt) {
            f32x16 aA = {}, aB = {};
            #pragma unroll
            for (int kk = 0; kk < 3; ++kk) {
                bf16x8 af = ld_frag(w0row + mt * 32 * W0P + kk * 16);
                aA = __builtin_amdgcn_mfma_f32_32x32x16_bf16(af, bf[0][kk].v, aA, 0, 0, 0);
                aB = __builtin_amdgcn_mfma_f32_32x32x16_bf16(af, bf[1][kk].v, aB, 0, 0, 0);
            }
            #pragma unroll
            for (int nt = 0; nt < 2; ++nt) {
                const f32x16& ac = nt ? aB : aA;
                FragU* hf = nt ? hf1 : hf0;
                unsigned p[8];
                #pragma unroll
                for (int r2 = 0; r2 < 8; ++r2)
                    p[r2] = pack2(fmaxf(ac[2 * r2], 0.f), fmaxf(ac[2 * r2 + 1], 0.f));
                unsigned g0[8], g1[8];
                #pragma unroll
                for (int r2 = 0; r2 < 8; ++r2) {
                    g0[r2] = __shfl(p[r2], nidx);
                    g1[r2] = __shfl(p[r2], nidx + 32);
                }
                hf[2 * mt + 0].u[0] = qh ? g0[2] : g0[0];
                hf[2 * mt + 0].u[1] = qh ? g0[3] : g0[1];
                hf[2 * mt + 0].u[2] = qh ? g1[2] : g1[0];
                hf[2 * mt + 0].u[3] = qh ? g1[3] : g1[1];
                hf[2 * mt + 1].u[0] = qh ? g0[6] : g0[4];
                hf[2 * mt + 1].u[1] = qh ? g0[7] : g0[5];
                hf[2 * mt + 1].u[2] = qh ? g1[6] : g1[4];
                hf[2 * mt + 1].u[3] = qh ? g1[7] : g1[5];
            }
        }

        // ---------------- layer1 MFMA + layer2 (fp32 VALU) --------------------
        float rA0 = 0.f, rA1 = 0.f, rA2 = 0.f;
        float rB0 = 0.f, rB1 = 0.f, rB2 = 0.f;
        const unsigned short* w1row = &s_w1a[nidx * W1P + qh * 8];
        #pragma unroll
        for (int mt2 = 0; mt2 < 4; ++mt2) {
            f32x16 cA = {}, cB = {};
            #pragma unroll
            for (int kk = 0; kk < 8; ++kk) {
                bf16x8 af = ld_frag(w1row + mt2 * 32 * W1P + kk * 16);
                cA = __builtin_amdgcn_mfma_f32_32x32x16_bf16(af, hf0[kk].v, cA, 0, 0, 0);
                cB = __builtin_amdgcn_mfma_f32_32x32x16_bf16(af, hf1[kk].v, cB, 0, 0, 0);
            }
            #pragma unroll
            for (int reg = 0; reg < 16; ++reg) {
                int dim = mt2 * 32 + (reg & 3) + 8 * (reg >> 2) + 4 * qh;
                float4 wb = s_w2b[dim];
                float hvA = fmaxf(cA[reg] + wb.w, 0.f);
                rA0 = fmaf(hvA, wb.x, rA0); rA1 = fmaf(hvA, wb.y, rA1); rA2 = fmaf(hvA, wb.z, rA2);
                float hvB = fmaxf(cB[reg] + wb.w, 0.f);
                rB0 = fmaf(hvB, wb.x, rB0); rB1 = fmaf(hvB, wb.y, rB1); rB2 = fmaf(hvB, wb.z, rB2);
            }
        }

        rA0 += __shfl_xor(rA0, 32); rA1 += __shfl_xor(rA1, 32); rA2 += __shfl_xor(rA2, 32);
        rB0 += __shfl_xor(rB0, 32); rB1 += __shfl_xor(rB1, 32); rB2 += __shfl_xor(rB2, 32);

        float wgtA = __shfl(wgt, nidx);
        float wgtB = __shfl(wgt, nidx + 32);
        float cA0 = wgtA * __builtin_amdgcn_rcpf(1.f + __expf(-(rA0 + b2x)));
        float cA1 = wgtA * __builtin_amdgcn_rcpf(1.f + __expf(-(rA1 + b2y)));
        float cA2 = wgtA * __builtin_amdgcn_rcpf(1.f + __expf(-(rA2 + b2z)));
        float cB0 = wgtB * __builtin_amdgcn_rcpf(1.f + __expf(-(rB0 + b2x)));
        float cB1 = wgtB * __builtin_amdgcn_rcpf(1.f + __expf(-(rB1 + b2y)));
        float cB2 = wgtB * __builtin_amdgcn_rcpf(1.f + __expf(-(rB2 + b2z)));

        float s0 = (lane < 32) ? (cA0 + cB0) : 0.f;
        float s1 = (lane < 32) ? (cA1 + cB1) : 0.f;
        float s2 = (lane < 32) ? (cA2 + cB2) : 0.f;
        #pragma unroll
        for (int off = 32; off > 0; off >>= 1) {
            s0 += __shfl_down(s0, off);
            s1 += __shfl_down(s1, off);
            s2 += __shfl_down(s2, off);
        }
        if (lane == 0) {
            s_red[par][w][0] = s0; s_red[par][w][1] = s1; s_red[par][w][2] = s2;
        }
        __syncthreads();
        if (t == 0) {
            out[ray * 3 + 0] = s_red[par][0][0] + s_red[par][1][0] + s_red[par][2][0] + s_red[par][3][0] + ainv;
            out[ray * 3 + 1] = s_red[par][0][1] + s_red[par][1][1] + s_red[par][2][1] + s_red[par][3][1] + ainv;
            out[ray * 3 + 2] = s_red[par][0][2] + s_red[par][1][2] + s_red[par][2][2] + s_red[par][3][2] + ainv;
        }
    }
}

extern "C" void kernel_launch(void* const* d_in, const int* in_sizes, int n_in,
                              void* d_out, int out_size, void* d_ws, size_t ws_size,
                              hipStream_t stream) {
    const float* ray_pts      = (const float*)d_in[0];
    const float* viewdirs     = (const float*)d_in[1];
    const float* density_grid = (const float*)d_in[2];
    const float* k0           = (const float*)d_in[3];
    const float* w0           = (const float*)d_in[4];
    const float* b0           = (const float*)d_in[5];
    const float* w1           = (const float*)d_in[6];
    const float* b1           = (const float*)d_in[7];
    const float* w2           = (const float*)d_in[8];
    const float* b2           = (const float*)d_in[9];
    float*       outp         = (float*)d_out;

    if (ws_size >= WS_NEED) {
        uint4* pk = (uint4*)d_ws;
        dvgo_prepack<<<dim3((NVOX + 255) / 256), dim3(256), 0, stream>>>(
            density_grid, k0, pk);
        dvgo_mfma<true><<<dim3(NRAYS / RPB), dim3(256), 0, stream>>>(
            ray_pts, viewdirs, density_grid, k0, pk, w0, b0, w1, b1, w2, b2, outp);
    } else {
        dvgo_mfma<false><<<dim3(NRAYS / RPB), dim3(256), 0, stream>>>(
            ray_pts, viewdirs, density_grid, k0, (const uint4*)d_ws,
            w0, b0, w1, b1, w2, b2, outp);
    }
}